// Round 9
// baseline (469.343 us; speedup 1.0000x reference)
//
#include <hip/hip_runtime.h>

#define N_NODES 100000
#define N_EDGES 1600000
#define DIM_IN  128
#define DIM_H   256
#define DIM_C   40

#define NB   391     // buckets of 256 nodes
#define NBLK 391     // edge chunks of 4096
#define CHUNK 4096
#define ECAP 6144    // LDS edge-cache capacity in k_build (ints)

typedef unsigned short bf16_t;
typedef __attribute__((ext_vector_type(8))) short short8;
typedef __attribute__((ext_vector_type(4))) float f32x4;

__device__ __forceinline__ bf16_t f2b(float f) {
    unsigned int u = __float_as_uint(f);
    unsigned int r = (u + 0x7fffu + ((u >> 16) & 1u)) >> 16;
    return (bf16_t)r;
}
__device__ __forceinline__ float b2f(unsigned int h16) {
    return __uint_as_float(h16 << 16);
}

__device__ __forceinline__ void gl_lds16(const void* gsrc, void* ldst) {
    __builtin_amdgcn_global_load_lds(
        (const __attribute__((address_space(1))) void*)gsrc,
        (__attribute__((address_space(3))) void*)ldst,
        16, 0, 0);
}

// ---------------- CSR build, two-phase binned ----------------

__global__ void k_bhist(const int* __restrict__ dst, int* __restrict__ cnt2, int e) {
    __shared__ int h[NB];
    int t = threadIdx.x, blk = blockIdx.x;
    for (int i = t; i < NB; i += 256) h[i] = 0;
    __syncthreads();
    int base = blk * CHUNK;
    int end = min(base + CHUNK, e);
    for (int i = base + t; i < end; i += 256)
        atomicAdd(&h[dst[i] >> 8], 1);
    __syncthreads();
    for (int i = t; i < NB; i += 256) cnt2[blk * NB + i] = h[i];
}

__global__ void k_bscanA(const int* __restrict__ cnt2, int* __restrict__ basep,
                         int* __restrict__ btot) {
    __shared__ int s[512];
    int t = threadIdx.x, b = blockIdx.x;
    int v = (t < NBLK) ? cnt2[t * NB + b] : 0;
    s[t] = v;
    __syncthreads();
    #pragma unroll
    for (int d = 1; d < 512; d <<= 1) {
        int tv = (t >= d) ? s[t - d] : 0;
        __syncthreads();
        s[t] += tv;
        __syncthreads();
    }
    if (t < NBLK) basep[t * NB + b] = s[t] - v;
    if (t == 511) btot[b] = s[511];
}

__global__ void k_bscan2(const int* __restrict__ btot, int* __restrict__ boff) {
    __shared__ int s[512];
    int t = threadIdx.x;
    int v = (t < NB) ? btot[t] : 0;
    s[t] = v;
    __syncthreads();
    #pragma unroll
    for (int d = 1; d < 512; d <<= 1) {
        int tv = (t >= d) ? s[t - d] : 0;
        __syncthreads();
        s[t] += tv;
        __syncthreads();
    }
    if (t < NB) boff[t] = s[t] - v;
    if (t == NB - 1) boff[NB] = s[t];
}

// packed ebuf word: src in bits 0..23 (src < 2^17), dst&255 in bits 24..31
__global__ void k_bscatter(const int* __restrict__ src, const int* __restrict__ dst,
                           const int* __restrict__ basep, const int* __restrict__ boff,
                           int* __restrict__ ebuf, int e) {
    __shared__ int cur[NB];
    int t = threadIdx.x, blk = blockIdx.x;
    for (int i = t; i < NB; i += 256) cur[i] = basep[blk * NB + i] + boff[i];
    __syncthreads();
    int base = blk * CHUNK;
    int end = min(base + CHUNK, e);
    for (int i = base + t; i < end; i += 256) {
        int sv = src[i], dv = dst[i];
        int pos = atomicAdd(&cur[dv >> 8], 1);
        ebuf[pos] = sv | ((dv & 255) << 24);
    }
}

__global__ __launch_bounds__(256) void k_build(const int* __restrict__ ebuf,
                                               const int* __restrict__ boff,
                                               int* __restrict__ off,
                                               int* __restrict__ csr) {
    __shared__ int ec[ECAP];
    __shared__ int h[256];
    __shared__ int cur[256];
    int t = threadIdx.x, b = blockIdx.x;
    int node0 = b << 8;
    int e0 = boff[b], e1 = boff[b + 1];
    int ne = e1 - e0;
    bool fits = (ne <= ECAP);
    h[t] = 0;
    __syncthreads();
    if (fits) {
        for (int i = t; i < ne; i += 256) {
            int p = ebuf[e0 + i];
            ec[i] = p;
            atomicAdd(&h[(unsigned)p >> 24], 1);
        }
    } else {
        for (int i = t; i < ne; i += 256)
            atomicAdd(&h[(unsigned)ebuf[e0 + i] >> 24], 1);
    }
    __syncthreads();
    int mydeg = h[t];
    #pragma unroll
    for (int d = 1; d < 256; d <<= 1) {
        int tv = (t >= d) ? h[t - d] : 0;
        __syncthreads();
        h[t] += tv;
        __syncthreads();
    }
    int node = node0 + t;
    if (node < N_NODES) off[node + 1] = e0 + h[t];
    if (b == 0 && t == 0) off[0] = 0;
    cur[t] = e0 + h[t] - mydeg;
    __syncthreads();
    if (fits) {
        for (int i = t; i < ne; i += 256) {
            int p = ec[i];
            int pos = atomicAdd(&cur[(unsigned)p >> 24], 1);
            csr[pos] = p & 0xFFFFFF;
        }
    } else {
        for (int i = t; i < ne; i += 256) {
            int p = ebuf[e0 + i];
            int pos = atomicAdd(&cur[(unsigned)p >> 24], 1);
            csr[pos] = p & 0xFFFFFF;
        }
    }
}

// ---------------- converts ----------------

// x fp32 [N][128] -> i8 per-row symmetric + row scale; one wave per row
__global__ void k_cvt_i8(const float* __restrict__ x, signed char* __restrict__ x8,
                         float* __restrict__ xs, int n) {
    int gid = blockIdx.x * blockDim.x + threadIdx.x;
    int u = gid >> 6, lane = gid & 63;
    if (u >= n) return;
    float2 v = *(const float2*)(x + (size_t)u * 128 + lane * 2);
    float m = fmaxf(fabsf(v.x), fabsf(v.y));
    #pragma unroll
    for (int d = 1; d < 64; d <<= 1)
        m = fmaxf(m, __shfl_xor(m, d, 64));
    float inv = (m > 0.f) ? 127.f / m : 0.f;
    int q0 = (int)rintf(v.x * inv);
    int q1 = (int)rintf(v.y * inv);
    unsigned short pk = (unsigned short)((q0 & 0xff) | ((q1 & 0xff) << 8));
    *(unsigned short*)(x8 + ((unsigned)u << 7) + lane * 2) = pk;
    if (lane == 0) xs[u] = (m > 0.f) ? m * (1.f / 127.f) : 0.f;
}

__global__ void k_wcvt(const float* __restrict__ w1a, const float* __restrict__ w1b,
                       const float* __restrict__ w2a, const float* __restrict__ w2b,
                       const float* __restrict__ fcw,
                       bf16_t* __restrict__ o1a, bf16_t* __restrict__ o1b,
                       bf16_t* __restrict__ o2a, bf16_t* __restrict__ o2b,
                       bf16_t* __restrict__ ofc) {
    int r = blockIdx.y;
    int idx = blockIdx.x * 256 + threadIdx.x;
    const float* in; bf16_t* out; int K, N, Npad;
    switch (r) {
        case 0: in = w1a; out = o1a; K = 128; N = 256; Npad = 256; break;
        case 1: in = w1b; out = o1b; K = 256; N = 256; Npad = 256; break;
        case 2: in = w2a; out = o2a; K = 256; N = 256; Npad = 256; break;
        case 3: in = w2b; out = o2b; K = 256; N = 256; Npad = 256; break;
        default: in = fcw; out = ofc; K = 256; N = 40;  Npad = 128; break;
    }
    if (idx >= Npad * K) return;
    int n = idx / K, k = idx - n * K;
    float v = (n < N) ? in[(size_t)k * N + n] : 0.f;
    out[idx] = f2b(v);
}

// ---------------- layer-1 aggregation (i8 row-scaled gather, D=128) ----------------
// one wave per node; lane covers 2 i8 cols (ushort load); 32-bit offsets

__global__ void k_agg_i8(const signed char* __restrict__ h8, const float* __restrict__ hs,
                         const int* __restrict__ off, const int* __restrict__ csr,
                         const float* __restrict__ eps_p,
                         bf16_t* __restrict__ rst, int n) {
    int gid = blockIdx.x * blockDim.x + threadIdx.x;
    int u = gid >> 6;
    int lane = gid & 63;
    if (u >= n) return;

    float acc0 = 0.f, acc1 = 0.f;
    int r0 = off[u], r1 = off[u + 1];
    int r = r0;
    unsigned loff = lane * 2u;
    for (; r + 8 <= r1; r += 8) {
        int s[8];
        #pragma unroll
        for (int t = 0; t < 8; t++) s[t] = csr[r + t];
        unsigned v[8];
        float sc[8];
        #pragma unroll
        for (int t = 0; t < 8; t++) {
            v[t] = *(const unsigned short*)(h8 + (((unsigned)s[t] << 7) + loff));
            sc[t] = hs[s[t]];
        }
        #pragma unroll
        for (int t = 0; t < 8; t++) {
            acc0 += (float)(int)(signed char)(v[t] & 0xffu) * sc[t];
            acc1 += (float)(int)(signed char)(v[t] >> 8) * sc[t];
        }
    }
    for (; r < r1; r++) {
        int s = csr[r];
        unsigned v = *(const unsigned short*)(h8 + (((unsigned)s << 7) + loff));
        float sc = hs[s];
        acc0 += (float)(int)(signed char)(v & 0xffu) * sc;
        acc1 += (float)(int)(signed char)(v >> 8) * sc;
    }

    float scu = hs[u] * (1.0f + eps_p[0]);
    unsigned vu = *(const unsigned short*)(h8 + (((unsigned)u << 7) + loff));
    float o0 = (float)(int)(signed char)(vu & 0xffu) * scu + acc0;
    float o1 = (float)(int)(signed char)(vu >> 8) * scu + acc1;
    *(unsigned int*)(rst + ((unsigned)u << 7) + lane * 2) =
        (unsigned int)f2b(o0) | ((unsigned int)f2b(o1) << 16);
}

// ---------------- layer-2 aggregation (u8 row-scaled gather, D=256) ----------------

__global__ void k_agg_u8(const unsigned char* __restrict__ h8,
                         const float* __restrict__ hs,
                         const int* __restrict__ off, const int* __restrict__ csr,
                         const float* __restrict__ eps_p,
                         bf16_t* __restrict__ rst, int n) {
    int gid = blockIdx.x * blockDim.x + threadIdx.x;
    int u = gid >> 6;
    int lane = gid & 63;
    if (u >= n) return;

    float acc[4] = {0.f, 0.f, 0.f, 0.f};
    int r0 = off[u], r1 = off[u + 1];
    int r = r0;
    unsigned loff = lane * 4u;
    for (; r + 8 <= r1; r += 8) {
        int s[8];
        #pragma unroll
        for (int t = 0; t < 8; t++) s[t] = csr[r + t];
        unsigned int v[8];
        float sc[8];
        #pragma unroll
        for (int t = 0; t < 8; t++) {
            v[t] = *(const unsigned int*)(h8 + (((unsigned)s[t] << 8) + loff));
            sc[t] = hs[s[t]];
        }
        #pragma unroll
        for (int t = 0; t < 8; t++) {
            acc[0] += (float)(v[t] & 0xffu) * sc[t];
            acc[1] += (float)((v[t] >> 8) & 0xffu) * sc[t];
            acc[2] += (float)((v[t] >> 16) & 0xffu) * sc[t];
            acc[3] += (float)(v[t] >> 24) * sc[t];
        }
    }
    for (; r < r1; r++) {
        int s = csr[r];
        unsigned int v = *(const unsigned int*)(h8 + (((unsigned)s << 8) + loff));
        float sc = hs[s];
        acc[0] += (float)(v & 0xffu) * sc;
        acc[1] += (float)((v >> 8) & 0xffu) * sc;
        acc[2] += (float)((v >> 16) & 0xffu) * sc;
        acc[3] += (float)(v >> 24) * sc;
    }

    float ep = 1.0f + eps_p[0];
    unsigned int vu = *(const unsigned int*)(h8 + (((unsigned)u << 8) + loff));
    float scu = hs[u] * ep;
    float o0 = (float)(vu & 0xffu) * scu + acc[0];
    float o1 = (float)((vu >> 8) & 0xffu) * scu + acc[1];
    float o2 = (float)((vu >> 16) & 0xffu) * scu + acc[2];
    float o3 = (float)(vu >> 24) * scu + acc[3];
    uint2 ov;
    ov.x = (unsigned int)f2b(o0) | ((unsigned int)f2b(o1) << 16);
    ov.y = (unsigned int)f2b(o2) | ((unsigned int)f2b(o3) << 16);
    *(uint2*)(rst + (size_t)u * 256 + lane * 4) = ov;
}

// ---------------- fused 2-GEMM MLP, 64-row tile ----------------
// OUT8: write u8 + per-row scale; else bf16.

#define TS_STRIDE 264

template <int K1, bool OUT8>
__global__ __launch_bounds__(256, 2) void k_mlp(
    const bf16_t* __restrict__ A, const bf16_t* __restrict__ W1t,
    const bf16_t* __restrict__ W2t, bf16_t* __restrict__ H,
    unsigned char* __restrict__ H8, float* __restrict__ Hs, int M)
{
    __shared__ __align__(16) bf16_t As[64 * 32];
    __shared__ __align__(16) bf16_t Bs[256 * 32];
    __shared__ __align__(16) bf16_t Ts[64 * TS_STRIDE];
    __shared__ int rmax[64];

    int tid = threadIdx.x;
    int wave = tid >> 6, lane = tid & 63;
    int l15 = lane & 15, quad = lane >> 4;
    int bm = blockIdx.x * 64;
    int wn = wave * 64;

    f32x4 acc[4][4];
    #pragma unroll
    for (int i = 0; i < 4; i++)
        #pragma unroll
        for (int j = 0; j < 4; j++) acc[i][j] = 0.f;

    // ---- phase 1 ----
    for (int k0 = 0; k0 < K1; k0 += 32) {
        {
            int row = tid >> 2, k8 = (tid & 3) * 8;
            int gr = bm + row; if (gr >= M) gr = M - 1;
            gl_lds16(A + (size_t)gr * K1 + k0 + k8, &As[(wave * 64) * 8]);
        }
        #pragma unroll
        for (int l = 0; l < 4; l++) {
            int s = l * 256 + tid;
            int row = s >> 2, k8 = (s & 3) * 8;
            gl_lds16(W1t + (size_t)row * K1 + k0 + k8, &Bs[(size_t)(l * 256 + wave * 64) * 8]);
        }
        __syncthreads();

        short8 af[4], bfv[4];
        #pragma unroll
        for (int i = 0; i < 4; i++)
            af[i] = *(const short8*)&As[(i * 16 + l15) * 32 + quad * 8];
        #pragma unroll
        for (int j = 0; j < 4; j++)
            bfv[j] = *(const short8*)&Bs[(wn + j * 16 + l15) * 32 + quad * 8];

        #pragma unroll
        for (int i = 0; i < 4; i++)
            #pragma unroll
            for (int j = 0; j < 4; j++)
                acc[i][j] = __builtin_amdgcn_mfma_f32_16x16x32_bf16(af[i], bfv[j], acc[i][j], 0, 0, 0);
        __syncthreads();
    }

    #pragma unroll
    for (int i = 0; i < 4; i++)
        #pragma unroll
        for (int j = 0; j < 4; j++) {
            int row = i * 16 + quad * 4;
            int col = wn + j * 16 + l15;
            #pragma unroll
            for (int r = 0; r < 4; r++)
                Ts[(row + r) * TS_STRIDE + col] = f2b(fmaxf(acc[i][j][r], 0.f));
        }

    #pragma unroll
    for (int i = 0; i < 4; i++)
        #pragma unroll
        for (int j = 0; j < 4; j++) acc[i][j] = 0.f;
    __syncthreads();

    // ---- phase 2 ----
    for (int k0 = 0; k0 < 256; k0 += 32) {
        #pragma unroll
        for (int l = 0; l < 4; l++) {
            int s = l * 256 + tid;
            int row = s >> 2, k8 = (s & 3) * 8;
            gl_lds16(W2t + (size_t)row * 256 + k0 + k8, &Bs[(size_t)(l * 256 + wave * 64) * 8]);
        }
        __syncthreads();

        short8 af[4], bfv[4];
        #pragma unroll
        for (int i = 0; i < 4; i++)
            af[i] = *(const short8*)&Ts[(i * 16 + l15) * TS_STRIDE + k0 + quad * 8];
        #pragma unroll
        for (int j = 0; j < 4; j++)
            bfv[j] = *(const short8*)&Bs[(wn + j * 16 + l15) * 32 + quad * 8];

        #pragma unroll
        for (int i = 0; i < 4; i++)
            #pragma unroll
            for (int j = 0; j < 4; j++)
                acc[i][j] = __builtin_amdgcn_mfma_f32_16x16x32_bf16(af[i], bfv[j], acc[i][j], 0, 0, 0);
        __syncthreads();
    }

    if constexpr (OUT8) {
        if (tid < 64) rmax[tid] = 0;
        __syncthreads();
        #pragma unroll
        for (int i = 0; i < 4; i++)
            #pragma unroll
            for (int r = 0; r < 4; r++) {
                float m = 0.f;
                #pragma unroll
                for (int j = 0; j < 4; j++) m = fmaxf(m, acc[i][j][r]);
                atomicMax(&rmax[i * 16 + quad * 4 + r], __float_as_int(m));
            }
        __syncthreads();
        #pragma unroll
        for (int i = 0; i < 4; i++) {
            #pragma unroll
            for (int r = 0; r < 4; r++) {
                int row = i * 16 + quad * 4 + r;
                int rowg = bm + row;
                if (rowg >= M) continue;
                float rm = __int_as_float(rmax[row]);
                float inv = (rm > 0.f) ? 255.f / rm : 0.f;
                #pragma unroll
                for (int j = 0; j < 4; j++) {
                    int col = wn + j * 16 + l15;
                    float v = fmaxf(acc[i][j][r], 0.f);
                    unsigned q = (unsigned)(v * inv + 0.5f);
                    if (q > 255u) q = 255u;
                    H8[(size_t)rowg * 256 + col] = (unsigned char)q;
                }
                if (wave == 0 && l15 == 0)
                    Hs[rowg] = rm * (1.f / 255.f);
            }
        }
    } else {
        #pragma unroll
        for (int j = 0; j < 4; j++) {
            int col = wn + j * 16 + l15;
            #pragma unroll
            for (int i = 0; i < 4; i++) {
                #pragma unroll
                for (int r = 0; r < 4; r++) {
                    int rowg = bm + i * 16 + quad * 4 + r;
                    if (rowg < M)
                        H[(size_t)rowg * 256 + col] = f2b(fmaxf(acc[i][j][r], 0.f));
                }
            }
        }
    }
}

// ---------------- fc GEMM ----------------

__global__ __launch_bounds__(256) void gemm_fc(
    const bf16_t* __restrict__ A, const bf16_t* __restrict__ Bt,
    const float* __restrict__ bias, float* __restrict__ C,
    int M, int K, int Nst)
{
    __shared__ __align__(16) bf16_t As[128 * 32];
    __shared__ __align__(16) bf16_t Bs[128 * 32];

    int tid = threadIdx.x;
    int wave = tid >> 6, lane = tid & 63;
    int l15 = lane & 15, quad = lane >> 4;
    int bm = blockIdx.y * 128, bn = blockIdx.x * 128;
    int wm = (wave >> 1) * 64, wn = (wave & 1) * 64;

    f32x4 acc[4][4];
    #pragma unroll
    for (int i = 0; i < 4; i++)
        #pragma unroll
        for (int j = 0; j < 4; j++) acc[i][j] = 0.f;

    for (int k0 = 0; k0 < K; k0 += 32) {
        #pragma unroll
        for (int iss = 0; iss < 2; iss++) {
            int s = iss * 256 + wave * 64 + lane;
            int row = s >> 2;
            int k8 = (s & 3) * 8;
            int ldsoff = (iss * 256 + wave * 64) * 8;

            int grA = bm + row; if (grA >= M) grA = M - 1;
            gl_lds16(A + (size_t)grA * K + k0 + k8, &As[ldsoff]);

            int grB = bn + row;
            gl_lds16(Bt + (size_t)grB * K + k0 + k8, &Bs[ldsoff]);
        }
        __syncthreads();

        short8 af[4], bfv[4];
        #pragma unroll
        for (int i = 0; i < 4; i++)
            af[i] = *(const short8*)&As[(wm + i * 16 + l15) * 32 + quad * 8];
        #pragma unroll
        for (int j = 0; j < 4; j++)
            bfv[j] = *(const short8*)&Bs[(wn + j * 16 + l15) * 32 + quad * 8];

        #pragma unroll
        for (int i = 0; i < 4; i++)
            #pragma unroll
            for (int j = 0; j < 4; j++)
                acc[i][j] = __builtin_amdgcn_mfma_f32_16x16x32_bf16(af[i], bfv[j], acc[i][j], 0, 0, 0);
        __syncthreads();
    }

    #pragma unroll
    for (int j = 0; j < 4; j++) {
        int col = bn + wn + j * 16 + l15;
        if (col >= Nst) continue;
        float bv = bias[col];
        #pragma unroll
        for (int i = 0; i < 4; i++) {
            #pragma unroll
            for (int r = 0; r < 4; r++) {
                int rowg = bm + wm + i * 16 + quad * 4 + r;
                if (rowg < M)
                    C[(size_t)rowg * Nst + col] = acc[i][j][r] + bv;
            }
        }
    }
}

// ---------------- launch ----------------

static inline size_t rnd256(size_t x) { return (x + 255) & ~(size_t)255; }

extern "C" void kernel_launch(void* const* d_in, const int* in_sizes, int n_in,
                              void* d_out, int out_size, void* d_ws, size_t ws_size,
                              hipStream_t stream) {
    const float* x    = (const float*)d_in[0];
    const int*   src  = (const int*)d_in[1];
    const int*   dst  = (const int*)d_in[2];
    const float* eps1 = (const float*)d_in[3];
    const float* w1a  = (const float*)d_in[4];
    const float* w1b  = (const float*)d_in[5];
    const float* eps2 = (const float*)d_in[6];
    const float* w2a  = (const float*)d_in[7];
    const float* w2b  = (const float*)d_in[8];
    const float* fc_w = (const float*)d_in[9];
    const float* fc_b = (const float*)d_in[10];
    float* out = (float*)d_out;

    char* w = (char*)d_ws;
    int* off  = (int*)w; w += rnd256(sizeof(int) * (size_t)(N_NODES + 1));
    int* csr  = (int*)w; w += rnd256(sizeof(int) * (size_t)N_EDGES);
    int* cnt2  = (int*)w; w += rnd256(sizeof(int) * (size_t)NBLK * NB);
    int* basep = (int*)w; w += rnd256(sizeof(int) * (size_t)NBLK * NB);
    int* btot  = (int*)w; w += rnd256(sizeof(int) * 512);
    int* boff  = (int*)w; w += rnd256(sizeof(int) * (NB + 1));
    bf16_t* w1a_t = (bf16_t*)w; w += rnd256(2 * (size_t)DIM_H * DIM_IN);
    bf16_t* w1b_t = (bf16_t*)w; w += rnd256(2 * (size_t)DIM_H * DIM_H);
    bf16_t* w2a_t = (bf16_t*)w; w += rnd256(2 * (size_t)DIM_H * DIM_H);
    bf16_t* w2b_t = (bf16_t*)w; w += rnd256(2 * (size_t)DIM_H * DIM_H);
    bf16_t* fc_t  = (bf16_t*)w; w += rnd256(2 * (size_t)128 * DIM_H);
    signed char* x8 = (signed char*)w; w += rnd256((size_t)N_NODES * DIM_IN);
    float* xs = (float*)w; w += rnd256(sizeof(float) * (size_t)N_NODES);
    unsigned char* h8 = (unsigned char*)w; w += rnd256((size_t)N_NODES * DIM_H);
    float* hs = (float*)w; w += rnd256(sizeof(float) * (size_t)N_NODES);
    bf16_t* R12 = (bf16_t*)w; w += rnd256(2 * (size_t)N_NODES * DIM_H);
    bf16_t* R3  = (bf16_t*)w; w += rnd256(2 * (size_t)N_NODES * DIM_H);

    bf16_t* rst1 = R12;       // [N][128] bf16
    int* ebuf = (int*)R3;     // 6.4 MB, dead before layer-2 agg writes R3

    // ---- CSR build ----
    k_bhist<<<NBLK, 256, 0, stream>>>(dst, cnt2, N_EDGES);
    k_bscanA<<<NB, 512, 0, stream>>>(cnt2, basep, btot);
    k_bscan2<<<1, 512, 0, stream>>>(btot, boff);
    k_bscatter<<<NBLK, 256, 0, stream>>>(src, dst, basep, boff, ebuf, N_EDGES);
    k_build<<<NB, 256, 0, stream>>>(ebuf, boff, off, csr);

    // ---- converts ----
    k_cvt_i8<<<(N_NODES * 64 + 255) / 256, 256, 0, stream>>>(x, x8, xs, N_NODES);
    {
        dim3 g(256, 5);
        k_wcvt<<<g, 256, 0, stream>>>(w1a, w1b, w2a, w2b, fc_w,
                                      w1a_t, w1b_t, w2a_t, w2b_t, fc_t);
    }

    const int agg_blocks = (N_NODES * 64 + 255) / 256;
    const int mlp_blocks = (N_NODES + 63) / 64;

    // ---- layer 1: i8 agg -> MLP (u8 output + row scales) ----
    k_agg_i8<<<agg_blocks, 256, 0, stream>>>(x8, xs, off, csr, eps1, rst1, N_NODES);
    k_mlp<DIM_IN, true><<<mlp_blocks, 256, 0, stream>>>(rst1, w1a_t, w1b_t,
                                                        nullptr, h8, hs, N_NODES);

    // ---- layer 2: u8 agg -> MLP (bf16 output) ----
    k_agg_u8<<<agg_blocks, 256, 0, stream>>>(h8, hs, off, csr, eps2, (bf16_t*)R3, N_NODES);
    k_mlp<DIM_H, false><<<mlp_blocks, 256, 0, stream>>>((bf16_t*)R3, w2a_t, w2b_t,
                                                        R12, nullptr, nullptr, N_NODES);

    // ---- classifier ----
    dim3 g1(1, (N_NODES + 127) / 128);
    gemm_fc<<<g1, 256, 0, stream>>>(R12, fc_t, fc_b, out, N_NODES, DIM_H, DIM_C);
}

// Round 10
// 442.988 us; speedup vs baseline: 1.0595x; 1.0595x over previous
//
#include <hip/hip_runtime.h>

#define N_NODES 100000
#define N_EDGES 1600000
#define DIM_IN  128
#define DIM_H   256
#define DIM_C   40

#define NB   391     // buckets of 256 nodes
#define NBLK 391     // edge chunks of 4096
#define CHUNK 4096
#define ECAP 6144    // LDS edge-cache capacity in k_build (ints)

typedef unsigned short bf16_t;
typedef __attribute__((ext_vector_type(8))) short short8;
typedef __attribute__((ext_vector_type(4))) float f32x4;

__device__ __forceinline__ bf16_t f2b(float f) {
    unsigned int u = __float_as_uint(f);
    unsigned int r = (u + 0x7fffu + ((u >> 16) & 1u)) >> 16;
    return (bf16_t)r;
}
__device__ __forceinline__ float b2f(unsigned int h16) {
    return __uint_as_float(h16 << 16);
}

__device__ __forceinline__ void gl_lds16(const void* gsrc, void* ldst) {
    __builtin_amdgcn_global_load_lds(
        (const __attribute__((address_space(1))) void*)gsrc,
        (__attribute__((address_space(3))) void*)ldst,
        16, 0, 0);
}

// ---------------- CSR build, two-phase binned ----------------

__global__ void k_bhist(const int* __restrict__ dst, int* __restrict__ cnt2, int e) {
    __shared__ int h[NB];
    int t = threadIdx.x, blk = blockIdx.x;
    for (int i = t; i < NB; i += 256) h[i] = 0;
    __syncthreads();
    int base = blk * CHUNK;
    int end = min(base + CHUNK, e);
    for (int i = base + t; i < end; i += 256)
        atomicAdd(&h[dst[i] >> 8], 1);
    __syncthreads();
    for (int i = t; i < NB; i += 256) cnt2[blk * NB + i] = h[i];
}

__global__ void k_bscanA(const int* __restrict__ cnt2, int* __restrict__ basep,
                         int* __restrict__ btot) {
    __shared__ int s[512];
    int t = threadIdx.x, b = blockIdx.x;
    int v = (t < NBLK) ? cnt2[t * NB + b] : 0;
    s[t] = v;
    __syncthreads();
    #pragma unroll
    for (int d = 1; d < 512; d <<= 1) {
        int tv = (t >= d) ? s[t - d] : 0;
        __syncthreads();
        s[t] += tv;
        __syncthreads();
    }
    if (t < NBLK) basep[t * NB + b] = s[t] - v;
    if (t == 511) btot[b] = s[511];
}

__global__ void k_bscan2(const int* __restrict__ btot, int* __restrict__ boff) {
    __shared__ int s[512];
    int t = threadIdx.x;
    int v = (t < NB) ? btot[t] : 0;
    s[t] = v;
    __syncthreads();
    #pragma unroll
    for (int d = 1; d < 512; d <<= 1) {
        int tv = (t >= d) ? s[t - d] : 0;
        __syncthreads();
        s[t] += tv;
        __syncthreads();
    }
    if (t < NB) boff[t] = s[t] - v;
    if (t == NB - 1) boff[NB] = s[t];
}

// packed ebuf word: src in bits 0..23 (src < 2^17), dst&255 in bits 24..31
__global__ void k_bscatter(const int* __restrict__ src, const int* __restrict__ dst,
                           const int* __restrict__ basep, const int* __restrict__ boff,
                           int* __restrict__ ebuf, int e) {
    __shared__ int cur[NB];
    int t = threadIdx.x, blk = blockIdx.x;
    for (int i = t; i < NB; i += 256) cur[i] = basep[blk * NB + i] + boff[i];
    __syncthreads();
    int base = blk * CHUNK;
    int end = min(base + CHUNK, e);
    for (int i = base + t; i < end; i += 256) {
        int sv = src[i], dv = dst[i];
        int pos = atomicAdd(&cur[dv >> 8], 1);
        ebuf[pos] = sv | ((dv & 255) << 24);
    }
}

__global__ __launch_bounds__(256) void k_build(const int* __restrict__ ebuf,
                                               const int* __restrict__ boff,
                                               int* __restrict__ off,
                                               int* __restrict__ csr) {
    __shared__ int ec[ECAP];
    __shared__ int h[256];
    __shared__ int cur[256];
    int t = threadIdx.x, b = blockIdx.x;
    int node0 = b << 8;
    int e0 = boff[b], e1 = boff[b + 1];
    int ne = e1 - e0;
    bool fits = (ne <= ECAP);
    h[t] = 0;
    __syncthreads();
    if (fits) {
        for (int i = t; i < ne; i += 256) {
            int p = ebuf[e0 + i];
            ec[i] = p;
            atomicAdd(&h[(unsigned)p >> 24], 1);
        }
    } else {
        for (int i = t; i < ne; i += 256)
            atomicAdd(&h[(unsigned)ebuf[e0 + i] >> 24], 1);
    }
    __syncthreads();
    int mydeg = h[t];
    #pragma unroll
    for (int d = 1; d < 256; d <<= 1) {
        int tv = (t >= d) ? h[t - d] : 0;
        __syncthreads();
        h[t] += tv;
        __syncthreads();
    }
    int node = node0 + t;
    if (node < N_NODES) off[node + 1] = e0 + h[t];
    if (b == 0 && t == 0) off[0] = 0;
    cur[t] = e0 + h[t] - mydeg;
    __syncthreads();
    if (fits) {
        for (int i = t; i < ne; i += 256) {
            int p = ec[i];
            int pos = atomicAdd(&cur[(unsigned)p >> 24], 1);
            csr[pos] = p & 0xFFFFFF;
        }
    } else {
        for (int i = t; i < ne; i += 256) {
            int p = ebuf[e0 + i];
            int pos = atomicAdd(&cur[(unsigned)p >> 24], 1);
            csr[pos] = p & 0xFFFFFF;
        }
    }
}

// ---------------- converts ----------------

// x fp32 [N][128] -> i8 per-row symmetric + row scale; one wave per row
__global__ void k_cvt_i8(const float* __restrict__ x, signed char* __restrict__ x8,
                         float* __restrict__ xs, int n) {
    int gid = blockIdx.x * blockDim.x + threadIdx.x;
    int u = gid >> 6, lane = gid & 63;
    if (u >= n) return;
    float2 v = *(const float2*)(x + (size_t)u * 128 + lane * 2);
    float m = fmaxf(fabsf(v.x), fabsf(v.y));
    #pragma unroll
    for (int d = 1; d < 64; d <<= 1)
        m = fmaxf(m, __shfl_xor(m, d, 64));
    float inv = (m > 0.f) ? 127.f / m : 0.f;
    int q0 = (int)rintf(v.x * inv);
    int q1 = (int)rintf(v.y * inv);
    unsigned short pk = (unsigned short)((q0 & 0xff) | ((q1 & 0xff) << 8));
    *(unsigned short*)(x8 + ((unsigned)u << 7) + lane * 2) = pk;
    if (lane == 0) xs[u] = (m > 0.f) ? m * (1.f / 127.f) : 0.f;
}

__global__ void k_wcvt(const float* __restrict__ w1a, const float* __restrict__ w1b,
                       const float* __restrict__ w2a, const float* __restrict__ w2b,
                       const float* __restrict__ fcw,
                       bf16_t* __restrict__ o1a, bf16_t* __restrict__ o1b,
                       bf16_t* __restrict__ o2a, bf16_t* __restrict__ o2b,
                       bf16_t* __restrict__ ofc) {
    int r = blockIdx.y;
    int idx = blockIdx.x * 256 + threadIdx.x;
    const float* in; bf16_t* out; int K, N, Npad;
    switch (r) {
        case 0: in = w1a; out = o1a; K = 128; N = 256; Npad = 256; break;
        case 1: in = w1b; out = o1b; K = 256; N = 256; Npad = 256; break;
        case 2: in = w2a; out = o2a; K = 256; N = 256; Npad = 256; break;
        case 3: in = w2b; out = o2b; K = 256; N = 256; Npad = 256; break;
        default: in = fcw; out = ofc; K = 256; N = 40;  Npad = 128; break;
    }
    if (idx >= Npad * K) return;
    int n = idx / K, k = idx - n * K;
    float v = (n < N) ? in[(size_t)k * N + n] : 0.f;
    out[idx] = f2b(v);
}

// ---------------- layer-1 aggregation (i8 gather, wave-uniform scalarized) ----------------
// u is wave-uniform -> readfirstlane makes off/csr/hs loads scalar (s_load) and
// row loads saddr-form; vector pipe issues 1 load per edge.

__global__ void k_agg_i8(const signed char* __restrict__ h8, const float* __restrict__ hs,
                         const int* __restrict__ off, const int* __restrict__ csr,
                         const float* __restrict__ eps_p,
                         bf16_t* __restrict__ rst, int n) {
    int gid = blockIdx.x * blockDim.x + threadIdx.x;
    int u = __builtin_amdgcn_readfirstlane(gid >> 6);   // wave-uniform
    int lane = threadIdx.x & 63;
    if (u >= n) return;

    float acc0 = 0.f, acc1 = 0.f;
    int r0 = off[u], r1 = off[u + 1];
    int r = r0;
    unsigned loff = lane * 2u;
    for (; r + 8 <= r1; r += 8) {
        int s[8];
        #pragma unroll
        for (int t = 0; t < 8; t++) s[t] = __builtin_amdgcn_readfirstlane(csr[r + t]);
        float sc[8];
        #pragma unroll
        for (int t = 0; t < 8; t++) sc[t] = hs[s[t]];           // scalar loads
        unsigned v[8];
        #pragma unroll
        for (int t = 0; t < 8; t++)
            v[t] = *(const unsigned short*)(h8 + (((unsigned)s[t] << 7) + loff));
        #pragma unroll
        for (int t = 0; t < 8; t++) {
            acc0 += (float)(int)(signed char)(v[t] & 0xffu) * sc[t];
            acc1 += (float)(int)(signed char)(v[t] >> 8) * sc[t];
        }
    }
    for (; r < r1; r++) {
        int s = __builtin_amdgcn_readfirstlane(csr[r]);
        float sc = hs[s];
        unsigned v = *(const unsigned short*)(h8 + (((unsigned)s << 7) + loff));
        acc0 += (float)(int)(signed char)(v & 0xffu) * sc;
        acc1 += (float)(int)(signed char)(v >> 8) * sc;
    }

    float scu = hs[u] * (1.0f + eps_p[0]);
    unsigned vu = *(const unsigned short*)(h8 + (((unsigned)u << 7) + loff));
    float o0 = (float)(int)(signed char)(vu & 0xffu) * scu + acc0;
    float o1 = (float)(int)(signed char)(vu >> 8) * scu + acc1;
    *(unsigned int*)(rst + ((unsigned)u << 7) + lane * 2) =
        (unsigned int)f2b(o0) | ((unsigned int)f2b(o1) << 16);
}

// ---------------- layer-2 aggregation (u8 gather, wave-uniform scalarized) ----------------

__global__ void k_agg_u8(const unsigned char* __restrict__ h8,
                         const float* __restrict__ hs,
                         const int* __restrict__ off, const int* __restrict__ csr,
                         const float* __restrict__ eps_p,
                         bf16_t* __restrict__ rst, int n) {
    int gid = blockIdx.x * blockDim.x + threadIdx.x;
    int u = __builtin_amdgcn_readfirstlane(gid >> 6);   // wave-uniform
    int lane = threadIdx.x & 63;
    if (u >= n) return;

    float acc[4] = {0.f, 0.f, 0.f, 0.f};
    int r0 = off[u], r1 = off[u + 1];
    int r = r0;
    unsigned loff = lane * 4u;
    for (; r + 8 <= r1; r += 8) {
        int s[8];
        #pragma unroll
        for (int t = 0; t < 8; t++) s[t] = __builtin_amdgcn_readfirstlane(csr[r + t]);
        float sc[8];
        #pragma unroll
        for (int t = 0; t < 8; t++) sc[t] = hs[s[t]];           // scalar loads
        unsigned int v[8];
        #pragma unroll
        for (int t = 0; t < 8; t++)
            v[t] = *(const unsigned int*)(h8 + (((unsigned)s[t] << 8) + loff));
        #pragma unroll
        for (int t = 0; t < 8; t++) {
            acc[0] += (float)(v[t] & 0xffu) * sc[t];
            acc[1] += (float)((v[t] >> 8) & 0xffu) * sc[t];
            acc[2] += (float)((v[t] >> 16) & 0xffu) * sc[t];
            acc[3] += (float)(v[t] >> 24) * sc[t];
        }
    }
    for (; r < r1; r++) {
        int s = __builtin_amdgcn_readfirstlane(csr[r]);
        float sc = hs[s];
        unsigned int v = *(const unsigned int*)(h8 + (((unsigned)s << 8) + loff));
        acc[0] += (float)(v & 0xffu) * sc;
        acc[1] += (float)((v >> 8) & 0xffu) * sc;
        acc[2] += (float)((v >> 16) & 0xffu) * sc;
        acc[3] += (float)(v >> 24) * sc;
    }

    float ep = 1.0f + eps_p[0];
    unsigned int vu = *(const unsigned int*)(h8 + (((unsigned)u << 8) + loff));
    float scu = hs[u] * ep;
    float o0 = (float)(vu & 0xffu) * scu + acc[0];
    float o1 = (float)((vu >> 8) & 0xffu) * scu + acc[1];
    float o2 = (float)((vu >> 16) & 0xffu) * scu + acc[2];
    float o3 = (float)(vu >> 24) * scu + acc[3];
    uint2 ov;
    ov.x = (unsigned int)f2b(o0) | ((unsigned int)f2b(o1) << 16);
    ov.y = (unsigned int)f2b(o2) | ((unsigned int)f2b(o3) << 16);
    *(uint2*)(rst + (size_t)u * 256 + lane * 4) = ov;
}

// ---------------- fused 2-GEMM MLP, 64-row tile ----------------
// OUT8: write u8 + per-row scale; else bf16.

#define TS_STRIDE 264

template <int K1, bool OUT8>
__global__ __launch_bounds__(256, 2) void k_mlp(
    const bf16_t* __restrict__ A, const bf16_t* __restrict__ W1t,
    const bf16_t* __restrict__ W2t, bf16_t* __restrict__ H,
    unsigned char* __restrict__ H8, float* __restrict__ Hs, int M)
{
    __shared__ __align__(16) bf16_t As[64 * 32];
    __shared__ __align__(16) bf16_t Bs[256 * 32];
    __shared__ __align__(16) bf16_t Ts[64 * TS_STRIDE];
    __shared__ int rmax[64];

    int tid = threadIdx.x;
    int wave = tid >> 6, lane = tid & 63;
    int l15 = lane & 15, quad = lane >> 4;
    int bm = blockIdx.x * 64;
    int wn = wave * 64;

    f32x4 acc[4][4];
    #pragma unroll
    for (int i = 0; i < 4; i++)
        #pragma unroll
        for (int j = 0; j < 4; j++) acc[i][j] = 0.f;

    // ---- phase 1 ----
    for (int k0 = 0; k0 < K1; k0 += 32) {
        {
            int row = tid >> 2, k8 = (tid & 3) * 8;
            int gr = bm + row; if (gr >= M) gr = M - 1;
            gl_lds16(A + (size_t)gr * K1 + k0 + k8, &As[(wave * 64) * 8]);
        }
        #pragma unroll
        for (int l = 0; l < 4; l++) {
            int s = l * 256 + tid;
            int row = s >> 2, k8 = (s & 3) * 8;
            gl_lds16(W1t + (size_t)row * K1 + k0 + k8, &Bs[(size_t)(l * 256 + wave * 64) * 8]);
        }
        __syncthreads();

        short8 af[4], bfv[4];
        #pragma unroll
        for (int i = 0; i < 4; i++)
            af[i] = *(const short8*)&As[(i * 16 + l15) * 32 + quad * 8];
        #pragma unroll
        for (int j = 0; j < 4; j++)
            bfv[j] = *(const short8*)&Bs[(wn + j * 16 + l15) * 32 + quad * 8];

        #pragma unroll
        for (int i = 0; i < 4; i++)
            #pragma unroll
            for (int j = 0; j < 4; j++)
                acc[i][j] = __builtin_amdgcn_mfma_f32_16x16x32_bf16(af[i], bfv[j], acc[i][j], 0, 0, 0);
        __syncthreads();
    }

    #pragma unroll
    for (int i = 0; i < 4; i++)
        #pragma unroll
        for (int j = 0; j < 4; j++) {
            int row = i * 16 + quad * 4;
            int col = wn + j * 16 + l15;
            #pragma unroll
            for (int r = 0; r < 4; r++)
                Ts[(row + r) * TS_STRIDE + col] = f2b(fmaxf(acc[i][j][r], 0.f));
        }

    #pragma unroll
    for (int i = 0; i < 4; i++)
        #pragma unroll
        for (int j = 0; j < 4; j++) acc[i][j] = 0.f;
    __syncthreads();

    // ---- phase 2 ----
    for (int k0 = 0; k0 < 256; k0 += 32) {
        #pragma unroll
        for (int l = 0; l < 4; l++) {
            int s = l * 256 + tid;
            int row = s >> 2, k8 = (s & 3) * 8;
            gl_lds16(W2t + (size_t)row * 256 + k0 + k8, &Bs[(size_t)(l * 256 + wave * 64) * 8]);
        }
        __syncthreads();

        short8 af[4], bfv[4];
        #pragma unroll
        for (int i = 0; i < 4; i++)
            af[i] = *(const short8*)&Ts[(i * 16 + l15) * TS_STRIDE + k0 + quad * 8];
        #pragma unroll
        for (int j = 0; j < 4; j++)
            bfv[j] = *(const short8*)&Bs[(wn + j * 16 + l15) * 32 + quad * 8];

        #pragma unroll
        for (int i = 0; i < 4; i++)
            #pragma unroll
            for (int j = 0; j < 4; j++)
                acc[i][j] = __builtin_amdgcn_mfma_f32_16x16x32_bf16(af[i], bfv[j], acc[i][j], 0, 0, 0);
        __syncthreads();
    }

    if constexpr (OUT8) {
        if (tid < 64) rmax[tid] = 0;
        __syncthreads();
        #pragma unroll
        for (int i = 0; i < 4; i++)
            #pragma unroll
            for (int r = 0; r < 4; r++) {
                float m = 0.f;
                #pragma unroll
                for (int j = 0; j < 4; j++) m = fmaxf(m, acc[i][j][r]);
                atomicMax(&rmax[i * 16 + quad * 4 + r], __float_as_int(m));
            }
        __syncthreads();
        #pragma unroll
        for (int i = 0; i < 4; i++) {
            #pragma unroll
            for (int r = 0; r < 4; r++) {
                int row = i * 16 + quad * 4 + r;
                int rowg = bm + row;
                if (rowg >= M) continue;
                float rm = __int_as_float(rmax[row]);
                float inv = (rm > 0.f) ? 255.f / rm : 0.f;
                #pragma unroll
                for (int j = 0; j < 4; j++) {
                    int col = wn + j * 16 + l15;
                    float v = fmaxf(acc[i][j][r], 0.f);
                    unsigned q = (unsigned)(v * inv + 0.5f);
                    if (q > 255u) q = 255u;
                    H8[(size_t)rowg * 256 + col] = (unsigned char)q;
                }
                if (wave == 0 && l15 == 0)
                    Hs[rowg] = rm * (1.f / 255.f);
            }
        }
    } else {
        #pragma unroll
        for (int j = 0; j < 4; j++) {
            int col = wn + j * 16 + l15;
            #pragma unroll
            for (int i = 0; i < 4; i++) {
                #pragma unroll
                for (int r = 0; r < 4; r++) {
                    int rowg = bm + i * 16 + quad * 4 + r;
                    if (rowg < M)
                        H[(size_t)rowg * 256 + col] = f2b(fmaxf(acc[i][j][r], 0.f));
                }
            }
        }
    }
}

// ---------------- fc GEMM ----------------

__global__ __launch_bounds__(256) void gemm_fc(
    const bf16_t* __restrict__ A, const bf16_t* __restrict__ Bt,
    const float* __restrict__ bias, float* __restrict__ C,
    int M, int K, int Nst)
{
    __shared__ __align__(16) bf16_t As[128 * 32];
    __shared__ __align__(16) bf16_t Bs[128 * 32];

    int tid = threadIdx.x;
    int wave = tid >> 6, lane = tid & 63;
    int l15 = lane & 15, quad = lane >> 4;
    int bm = blockIdx.y * 128, bn = blockIdx.x * 128;
    int wm = (wave >> 1) * 64, wn = (wave & 1) * 64;

    f32x4 acc[4][4];
    #pragma unroll
    for (int i = 0; i < 4; i++)
        #pragma unroll
        for (int j = 0; j < 4; j++) acc[i][j] = 0.f;

    for (int k0 = 0; k0 < K; k0 += 32) {
        #pragma unroll
        for (int iss = 0; iss < 2; iss++) {
            int s = iss * 256 + wave * 64 + lane;
            int row = s >> 2;
            int k8 = (s & 3) * 8;
            int ldsoff = (iss * 256 + wave * 64) * 8;

            int grA = bm + row; if (grA >= M) grA = M - 1;
            gl_lds16(A + (size_t)grA * K + k0 + k8, &As[ldsoff]);

            int grB = bn + row;
            gl_lds16(Bt + (size_t)grB * K + k0 + k8, &Bs[ldsoff]);
        }
        __syncthreads();

        short8 af[4], bfv[4];
        #pragma unroll
        for (int i = 0; i < 4; i++)
            af[i] = *(const short8*)&As[(wm + i * 16 + l15) * 32 + quad * 8];
        #pragma unroll
        for (int j = 0; j < 4; j++)
            bfv[j] = *(const short8*)&Bs[(wn + j * 16 + l15) * 32 + quad * 8];

        #pragma unroll
        for (int i = 0; i < 4; i++)
            #pragma unroll
            for (int j = 0; j < 4; j++)
                acc[i][j] = __builtin_amdgcn_mfma_f32_16x16x32_bf16(af[i], bfv[j], acc[i][j], 0, 0, 0);
        __syncthreads();
    }

    #pragma unroll
    for (int j = 0; j < 4; j++) {
        int col = bn + wn + j * 16 + l15;
        if (col >= Nst) continue;
        float bv = bias[col];
        #pragma unroll
        for (int i = 0; i < 4; i++) {
            #pragma unroll
            for (int r = 0; r < 4; r++) {
                int rowg = bm + wm + i * 16 + quad * 4 + r;
                if (rowg < M)
                    C[(size_t)rowg * Nst + col] = acc[i][j][r] + bv;
            }
        }
    }
}

// ---------------- launch ----------------

static inline size_t rnd256(size_t x) { return (x + 255) & ~(size_t)255; }

extern "C" void kernel_launch(void* const* d_in, const int* in_sizes, int n_in,
                              void* d_out, int out_size, void* d_ws, size_t ws_size,
                              hipStream_t stream) {
    const float* x    = (const float*)d_in[0];
    const int*   src  = (const int*)d_in[1];
    const int*   dst  = (const int*)d_in[2];
    const float* eps1 = (const float*)d_in[3];
    const float* w1a  = (const float*)d_in[4];
    const float* w1b  = (const float*)d_in[5];
    const float* eps2 = (const float*)d_in[6];
    const float* w2a  = (const float*)d_in[7];
    const float* w2b  = (const float*)d_in[8];
    const float* fc_w = (const float*)d_in[9];
    const float* fc_b = (const float*)d_in[10];
    float* out = (float*)d_out;

    char* w = (char*)d_ws;
    int* off  = (int*)w; w += rnd256(sizeof(int) * (size_t)(N_NODES + 1));
    int* csr  = (int*)w; w += rnd256(sizeof(int) * (size_t)N_EDGES);
    int* cnt2  = (int*)w; w += rnd256(sizeof(int) * (size_t)NBLK * NB);
    int* basep = (int*)w; w += rnd256(sizeof(int) * (size_t)NBLK * NB);
    int* btot  = (int*)w; w += rnd256(sizeof(int) * 512);
    int* boff  = (int*)w; w += rnd256(sizeof(int) * (NB + 1));
    bf16_t* w1a_t = (bf16_t*)w; w += rnd256(2 * (size_t)DIM_H * DIM_IN);
    bf16_t* w1b_t = (bf16_t*)w; w += rnd256(2 * (size_t)DIM_H * DIM_H);
    bf16_t* w2a_t = (bf16_t*)w; w += rnd256(2 * (size_t)DIM_H * DIM_H);
    bf16_t* w2b_t = (bf16_t*)w; w += rnd256(2 * (size_t)DIM_H * DIM_H);
    bf16_t* fc_t  = (bf16_t*)w; w += rnd256(2 * (size_t)128 * DIM_H);
    signed char* x8 = (signed char*)w; w += rnd256((size_t)N_NODES * DIM_IN);
    float* xs = (float*)w; w += rnd256(sizeof(float) * (size_t)N_NODES);
    unsigned char* h8 = (unsigned char*)w; w += rnd256((size_t)N_NODES * DIM_H);
    float* hs = (float*)w; w += rnd256(sizeof(float) * (size_t)N_NODES);
    bf16_t* R12 = (bf16_t*)w; w += rnd256(2 * (size_t)N_NODES * DIM_H);
    bf16_t* R3  = (bf16_t*)w; w += rnd256(2 * (size_t)N_NODES * DIM_H);

    bf16_t* rst1 = R12;       // [N][128] bf16
    int* ebuf = (int*)R3;     // 6.4 MB, dead before layer-2 agg writes R3

    // ---- CSR build ----
    k_bhist<<<NBLK, 256, 0, stream>>>(dst, cnt2, N_EDGES);
    k_bscanA<<<NB, 512, 0, stream>>>(cnt2, basep, btot);
    k_bscan2<<<1, 512, 0, stream>>>(btot, boff);
    k_bscatter<<<NBLK, 256, 0, stream>>>(src, dst, basep, boff, ebuf, N_EDGES);
    k_build<<<NB, 256, 0, stream>>>(ebuf, boff, off, csr);

    // ---- converts ----
    k_cvt_i8<<<(N_NODES * 64 + 255) / 256, 256, 0, stream>>>(x, x8, xs, N_NODES);
    {
        dim3 g(256, 5);
        k_wcvt<<<g, 256, 0, stream>>>(w1a, w1b, w2a, w2b, fc_w,
                                      w1a_t, w1b_t, w2a_t, w2b_t, fc_t);
    }

    const int agg_blocks = (N_NODES * 64 + 255) / 256;
    const int mlp_blocks = (N_NODES + 63) / 64;

    // ---- layer 1: i8 agg -> MLP (u8 output + row scales) ----
    k_agg_i8<<<agg_blocks, 256, 0, stream>>>(x8, xs, off, csr, eps1, rst1, N_NODES);
    k_mlp<DIM_IN, true><<<mlp_blocks, 256, 0, stream>>>(rst1, w1a_t, w1b_t,
                                                        nullptr, h8, hs, N_NODES);

    // ---- layer 2: u8 agg -> MLP (bf16 output) ----
    k_agg_u8<<<agg_blocks, 256, 0, stream>>>(h8, hs, off, csr, eps2, (bf16_t*)R3, N_NODES);
    k_mlp<DIM_H, false><<<mlp_blocks, 256, 0, stream>>>((bf16_t*)R3, w2a_t, w2b_t,
                                                        R12, nullptr, nullptr, N_NODES);

    // ---- classifier ----
    dim3 g1(1, (N_NODES + 127) / 128);
    gemm_fc<<<g1, 256, 0, stream>>>(R12, fc_t, fc_b, out, N_NODES, DIM_H, DIM_C);
}